// Round 6
// baseline (129.937 us; speedup 1.0000x reference)
//
#include <hip/hip_runtime.h>
#include <cstdint>

#define NRAD 4096
#define NLID 16384
#define KMIX 8
#define TOPK 10
#define CF   16
#define NBIN 176
#define YWIN 13
#define LOG2PI 1.8378770664093453f

static constexpr unsigned INF_D2 = 62851u;   // > max real d2 (40^2 + 2*175^2 = 62850)

// ---------------------------------------------------------------- helpers
__device__ __forceinline__ void insert_key(unsigned (&t)[TOPK], unsigned key) {
    // t ascending; branch-free exact insert of key into 10 smallest.
#pragma unroll
    for (int i = TOPK - 1; i >= 1; --i) {
        unsigned hi = key > t[i - 1] ? key : t[i - 1];
        t[i] = hi < t[i] ? hi : t[i];
    }
    t[0] = key < t[0] ? key : t[0];
}

__device__ __forceinline__ void merge10(unsigned (&t)[TOPK], int lane,
                                        unsigned& mine, unsigned& first, unsigned& tenth) {
#pragma unroll
    for (int r = 0; r < TOPK; ++r) {
        unsigned v = t[0];
#pragma unroll
        for (int off = 32; off >= 1; off >>= 1) {
            unsigned o = __shfl_xor(v, off, 64);
            v = o < v ? o : v;
        }
        if (t[0] == v) {                       // unique keys -> exactly one popper
#pragma unroll
            for (int i = 0; i < TOPK - 1; ++i) t[i] = t[i + 1];
            t[TOPK - 1] = 0xFFFFFFFFu;
        }
        if (lane == r) mine = v;
        if (r == 0) first = v;
        if (r == TOPK - 1) tenth = v;
    }
}

__device__ __forceinline__ float waveReduceSum(float v) {
#pragma unroll
    for (int off = 32; off >= 1; off >>= 1) v += __shfl_down(v, off, 64);
    return v;
}

// scan candidates in [s,e) of a y-sorted batch partition (uint2, for rescans)
__device__ __forceinline__ void scan_range(unsigned (&t)[TOPK], const uint2* __restrict__ base,
                                           int s, int e, int rz, int ry, int rx, int lane) {
    for (int i = s + lane; i < e; i += 64) {
        uint2 c = base[i];
        int dz = (int)((c.x >> 16) & 63u)  - rz;
        int dy = (int)((c.x >> 8)  & 255u) - ry;
        int dx = (int)(c.x & 255u)         - rx;
        unsigned d2 = (unsigned)(__mul24(dz, dz) + __mul24(dy, dy) + __mul24(dx, dx));
        unsigned key = (d2 << 14) | c.y;
        if (key < t[TOPK - 1]) insert_key(t, key);
    }
}

// ---------------------------------------------------------------- prep
// 4 blocks x 1024 threads; block b owns batch b. Counting-sort the batch's
// lidar by y (176 bins) into compacted; LDS histogram + wave-parallel shfl
// prefix scan. Emits per-batch bin offsets so topk can scan a y-window.
// Block 0 zeroes the (64B-strided) accumulators + dctr for the fused kernel.
__global__ __launch_bounds__(1024) void prep_kernel(
        const int* __restrict__ lidar_indices,
        unsigned* __restrict__ packed_full,
        uint2* __restrict__ compacted,
        int* __restrict__ binoff_g,
        float* __restrict__ accum,            // strided: accum[k*16], k=0..3
        unsigned* __restrict__ dctr) {
    __shared__ int hist[NBIN];
    __shared__ int binoff_s[NBIN + 1];
    __shared__ int bcur[NBIN];
    int tid = threadIdx.x, myb = blockIdx.x;
    if (tid < NBIN) hist[tid] = 0;

    // stage ALL loads up-front (static indices -> registers, latencies overlap)
    int4 li[NLID / 1024];
#pragma unroll
    for (int it = 0; it < NLID / 1024; ++it)
        li[it] = ((const int4*)lidar_indices)[it * 1024 + tid];
    __syncthreads();

    // histogram over y (= column 2, li.z)
#pragma unroll
    for (int it = 0; it < NLID / 1024; ++it)
        if (li[it].x == myb) atomicAdd(&hist[li[it].z], 1);
    __syncthreads();

    // exclusive prefix: wave 0 only, shfl_up scan over 3 chunks of 64
    if (tid < 64) {
        int carry = 0;
#pragma unroll
        for (int c = 0; c < 3; ++c) {
            int idx = c * 64 + tid;
            int h = (idx < NBIN) ? hist[idx] : 0;
            int v = h;
#pragma unroll
            for (int off = 1; off < 64; off <<= 1) {
                int u = __shfl_up(v, off, 64);
                if (tid >= off) v += u;
            }
            if (idx < NBIN) binoff_s[idx] = carry + v - h;   // exclusive
            carry += __shfl(v, 63, 64);
        }
        if (tid == 0) binoff_s[NBIN] = carry;
    }
    __syncthreads();
    if (tid < NBIN) bcur[tid] = binoff_s[tid];
    __syncthreads();

    // scatter: y-sorted compacted + packed_full for the degenerate fallback
#pragma unroll
    for (int it = 0; it < NLID / 1024; ++it) {
        int i = it * 1024 + tid;
        unsigned pos = ((unsigned)li[it].y << 16) | ((unsigned)li[it].z << 8) | (unsigned)li[it].w;
        if (li[it].x == myb) {
            packed_full[i] = ((unsigned)li[it].x << 22) | pos;
            int dst = atomicAdd(&bcur[li[it].z], 1);
            compacted[myb * NLID + dst] = make_uint2(pos, (unsigned)i);
        }
    }

    __syncthreads();
    if (tid <= NBIN) binoff_g[myb * (NBIN + 1) + tid] = binoff_s[tid];
    if (myb == 0) {
        if (tid >= 64 && tid < 68) accum[(tid - 64) * 16] = 0.f;
        if (tid == 68) *dctr = 0u;
    }
}

// ---------------------------------------------------------------- fused top-10 NN + MDN
// One wave per radar row (4 rows/block). y-window scan (|dy|<=13, ~630 cands,
// uint4 2-cand/lane iters) with exact accept test; rare reject rescans the
// remaining strips; <10-in-batch rows use the full packed scan. Then the
// block's 4 waves hand {row, matched, nn[10]} to LDS; wave 0 alone computes
// the 40 MDN pairs (one pair per lane -> total MDN work == the old dedicated
// dispatch, NOT round-3's 6.4x redundancy), reduces in-wave, and atomically
// accumulates into 64B-strided slots. Last block finalizes out[0].
__global__ __launch_bounds__(256) void topk_mdn_kernel(
        const uint2* __restrict__ compacted,
        const unsigned* __restrict__ packed_full,
        const int* __restrict__ binoff_g,
        const int* __restrict__ radar_indices,
        const int* __restrict__ lidar_indices,
        const float* __restrict__ mu_off, const float* __restrict__ log_sig_off,
        const float* __restrict__ mu_int, const float* __restrict__ occ_logit,
        const float* __restrict__ mix_logit, const float* __restrict__ lidar_features,
        float* __restrict__ accum,            // strided: accum[k*16]
        unsigned* __restrict__ dctr,
        float* __restrict__ out) {
    int lane = threadIdx.x & 63;
    int wid  = threadIdx.x >> 6;
    int row  = blockIdx.x * 4 + wid;
    int4 ri = ((const int4*)radar_indices)[row];
    int rb = ri.x, rz = ri.y, ry = ri.z, rx = ri.w;
    const int* boff = binoff_g + rb * (NBIN + 1);

    int lo = ry - YWIN;      lo = lo < 0 ? 0 : lo;
    int hi = ry + YWIN + 1;  hi = hi > NBIN ? NBIN : hi;
    int s = boff[lo], e = boff[hi];

    unsigned t[TOPK];
#pragma unroll
    for (int i = 0; i < TOPK; ++i) t[i] = 0xFFFFFFFFu;

    const uint2* base = compacted + rb * NLID;
    int s0 = s & ~1;                                     // even -> 16B aligned
    const uint4* src4 = (const uint4*)(base + s0);
    int iters = (e - s0 + 127) >> 7;
    uint4 q = src4[lane];                                // stays in-partition
    for (int it = 0; it < iters; ++it) {
        uint4 qn = q;
        if (it + 1 < iters) qn = src4[(it + 1) * 64 + lane];   // prefetch next
        int p = s0 + (it * 64 + lane) * 2;
        {
            int dz = (int)((q.x >> 16) & 63u)  - rz;
            int dy = (int)((q.x >> 8)  & 255u) - ry;
            int dx = (int)(q.x & 255u)         - rx;
            unsigned d2 = (unsigned)(__mul24(dz, dz) + __mul24(dy, dy) + __mul24(dx, dx));
            unsigned key = (p >= s && p < e) ? ((d2 << 14) | q.y) : 0xFFFFFFFFu;
            if (key < t[TOPK - 1]) insert_key(t, key);
        }
        {
            int dz = (int)((q.z >> 16) & 63u)  - rz;
            int dy = (int)((q.z >> 8)  & 255u) - ry;
            int dx = (int)(q.z & 255u)         - rx;
            unsigned d2 = (unsigned)(__mul24(dz, dz) + __mul24(dy, dy) + __mul24(dx, dx));
            unsigned key = (p + 1 < e) ? ((d2 << 14) | q.w) : 0xFFFFFFFFu;
            if (key < t[TOPK - 1]) insert_key(t, key);
        }
        q = qn;
    }

    unsigned mine = 0xFFFFFFFFu, first = 0, tenth = 0;
    merge10(t, lane, mine, first, tenth);
    bool matched = true;

    // closest possible d2 outside the window (INF if window clipped that side)
    unsigned lim = 0xFFFFFFFFu;
    if (lo > 0)    { unsigned d = (unsigned)(ry - lo + 1); unsigned v = d * d; lim = v < lim ? v : lim; }
    if (hi < NBIN) { unsigned d = (unsigned)(hi - ry);     unsigned v = d * d; lim = v < lim ? v : lim; }

    if ((tenth >> 14) >= lim) {
        // expand to the full batch range, excluding already-scanned [s,e)
#pragma unroll
        for (int i = 0; i < TOPK; ++i) t[i] = 0xFFFFFFFFu;
        t[0] = mine;                                   // reseed (lanes>=10: FFFF no-op)
        scan_range(t, base, boff[0], s, rz, ry, rx, lane);
        scan_range(t, base, e, boff[NBIN], rz, ry, rx, lane);
        merge10(t, lane, mine, first, tenth);
    }

    if (tenth == 0xFFFFFFFFu) {
        // Degenerate row (<10 same-batch lidar): exact full scan w/ INF keys.
#pragma unroll
        for (int i = 0; i < TOPK; ++i) t[i] = 0xFFFFFFFFu;
        for (int it = 0; it < NLID / 256; ++it) {
            uint4 p4 = ((const uint4*)packed_full)[it * 64 + lane];
            unsigned bse = it * 256 + lane * 4;
            unsigned ps[4] = {p4.x, p4.y, p4.z, p4.w};
#pragma unroll
            for (int j = 0; j < 4; ++j) {
                unsigned p = ps[j];
                int b  = (int)(p >> 22);
                int dz = (int)((p >> 16) & 63u)  - rz;
                int dy = (int)((p >> 8)  & 255u) - ry;
                int dx = (int)(p & 255u)         - rx;
                unsigned d2 = (unsigned)(__mul24(dz, dz) + __mul24(dy, dy) + __mul24(dx, dx));
                unsigned hi2 = (b == rb) ? d2 : INF_D2;
                insert_key(t, (hi2 << 14) | (bse + j));
            }
        }
        merge10(t, lane, mine, first, tenth);
        matched = first < (INF_D2 << 14);
    }

    // ---------------- hand off to wave 0 via LDS (192 B) ------------------
    __shared__ int   s_nn[4][TOPK];
    __shared__ int   s_row[4];
    __shared__ float s_mf[4];
    if (lane < TOPK) s_nn[wid][lane] = (int)(mine & 0x3FFFu);
    if (lane == 0) { s_row[wid] = row; s_mf[wid] = matched ? 1.f : 0.f; }
    __syncthreads();
    if (wid != 0) return;                  // waves 1-3 done; wave 0 owns 40 pairs

    bool act = lane < 4 * TOPK;
    int w  = lane / TOPK;                  // 0..3 (garbage for inactive: masked)
    int tt = lane - w * TOPK;
    int n   = act ? s_row[w] : 0;
    float mf = act ? s_mf[w] : 0.f;
    int nni = act ? s_nn[w][tt] : 0;

    int4 rr = ((const int4*)radar_indices)[n];
    int4 li = ((const int4*)lidar_indices)[nni];
    float y0 = mf * (float)(li.w - rr.w);
    float y1 = mf * (float)(li.z - rr.z);
    float y2 = mf * (float)(li.y - rr.y);

    float mix[KMIX];
    float mmax = -1e30f;
#pragma unroll
    for (int k = 0; k < KMIX; ++k) {
        mix[k] = mix_logit[n * KMIX + k];
        mmax = fmaxf(mmax, mix[k]);
    }
    float msum = 0.f;
#pragma unroll
    for (int k = 0; k < KMIX; ++k) msum += expf(mix[k] - mmax);
    float logZ = mmax + logf(msum);

    float lpost[KMIX];
    float pmax = -1e30f;
#pragma unroll
    for (int k = 0; k < KMIX; ++k) {
        int bidx = (n * KMIX + k) * 3;
        float mu0 = mu_off[bidx + 0], mu1 = mu_off[bidx + 1], mu2 = mu_off[bidx + 2];
        float l0 = log_sig_off[bidx + 0], l1 = log_sig_off[bidx + 1], l2 = log_sig_off[bidx + 2];
        float s0 = expf(2.f * l0) + 1e-12f;
        float s1 = expf(2.f * l1) + 1e-12f;
        float s2 = expf(2.f * l2) + 1e-12f;
        float d0 = y0 - mu0, d1 = y1 - mu1, d2v = y2 - mu2;
        float qv = d0 * d0 / s0 + d1 * d1 / s1 + d2v * d2v / s2
                 + 2.f * (l0 + l1 + l2) + 3.f * LOG2PI;
        lpost[k] = -0.5f * qv + (mix[k] - logZ);
        pmax = fmaxf(pmax, lpost[k]);
    }
    float ex[KMIX];
    float se = 0.f;
#pragma unroll
    for (int k = 0; k < KMIX; ++k) { ex[k] = expf(lpost[k] - pmax); se += ex[k]; }
    float logp = pmax + logf(se);

    float gt = 0.f;
    if (act && mf != 0.f) {
        const float* lf = lidar_features + nni * CF;
        gt = 0.25f * (lf[3] + lf[7] + lf[11] + lf[15]);
    }
    float inv_se = 1.f / se;
    float isum = 0.f;
#pragma unroll
    for (int k = 0; k < KMIX; ++k)
        isum += ex[k] * inv_se * fabsf(mu_int[n * KMIX + k] - gt);

    float lp = act ? mf * logp : 0.f;
    float ip = act ? mf * isum : 0.f;
    float oc = 0.f, mc = 0.f;
    if (act && tt == 0) {
        float oa = -1e30f;
#pragma unroll
        for (int k = 0; k < KMIX; ++k) oa = fmaxf(oa, occ_logit[n * KMIX + k]);
        float soft_abs = log1pf(expf(-fabsf(oa)));
        oc = mf * (soft_abs + fmaxf(-oa, 0.f)) + (1.f - mf) * (soft_abs + fmaxf(oa, 0.f));
        mc = mf;
    }

    lp = waveReduceSum(lp); ip = waveReduceSum(ip);
    oc = waveReduceSum(oc); mc = waveReduceSum(mc);
    if (lane == 0) {
        atomicAdd(&accum[0],  lp);
        atomicAdd(&accum[16], ip);
        atomicAdd(&accum[32], oc);
        atomicAdd(&accum[48], mc);
        __threadfence();
        unsigned done = atomicAdd(dctr, 1u);
        if (done == gridDim.x - 1) {          // last block finalizes
            __threadfence();
            float a = __hip_atomic_load(&accum[0],  __ATOMIC_RELAXED, __HIP_MEMORY_SCOPE_AGENT);
            float b = __hip_atomic_load(&accum[16], __ATOMIC_RELAXED, __HIP_MEMORY_SCOPE_AGENT);
            float c = __hip_atomic_load(&accum[32], __ATOMIC_RELAXED, __HIP_MEMORY_SCOPE_AGENT);
            float d = __hip_atomic_load(&accum[48], __ATOMIC_RELAXED, __HIP_MEMORY_SCOPE_AGENT);
            float occ_loss = c / (float)NRAD;
            float mdn_nll  = -a / (d * (float)TOPK);
            float int_loss = b / (d * (float)TOPK * (float)KMIX);
            out[0] = 0.2f * occ_loss + mdn_nll + 0.1f * int_loss;
        }
    }
}

// ---------------------------------------------------------------- launch
extern "C" void kernel_launch(void* const* d_in, const int* in_sizes, int n_in,
                              void* d_out, int out_size, void* d_ws, size_t ws_size,
                              hipStream_t stream) {
    const float* mu_off         = (const float*)d_in[0];
    const float* log_sig_off    = (const float*)d_in[1];
    const float* mu_int         = (const float*)d_in[2];
    const float* occ_logit      = (const float*)d_in[3];
    const float* mix_logit      = (const float*)d_in[4];
    const float* lidar_features = (const float*)d_in[5];
    const int*   radar_indices  = (const int*)d_in[6];
    const int*   lidar_indices  = (const int*)d_in[7];
    float* out = (float*)d_out;

    char* ws = (char*)d_ws;
    unsigned* packed_full = (unsigned*)(ws + 0);         //  64 KB
    uint2*    compacted   = (uint2*)(ws + 65536);        //  512 KB (y-sorted per batch)
    int*      binoff_g    = (int*)(ws + 589824);         //  4*177*4 = 2832 B
    float*    accum       = (float*)(ws + 593920);       //  4 slots @ 64B stride
    unsigned* dctr        = (unsigned*)(ws + 594176);    //  4 B

    hipLaunchKernelGGL(prep_kernel, dim3(4), dim3(1024), 0, stream,
                       lidar_indices, packed_full, compacted, binoff_g, accum, dctr);
    hipLaunchKernelGGL(topk_mdn_kernel, dim3(NRAD / 4), dim3(256), 0, stream,
                       compacted, packed_full, binoff_g, radar_indices, lidar_indices,
                       mu_off, log_sig_off, mu_int, occ_logit, mix_logit,
                       lidar_features, accum, dctr, out);
}

// Round 7
// 104.606 us; speedup vs baseline: 1.2422x; 1.2422x over previous
//
#include <hip/hip_runtime.h>
#include <cstdint>

#define NRAD 4096
#define NLID 16384
#define KMIX 8
#define TOPK 10
#define CF   16
#define NBIN 176
#define YWIN 13
#define LOG2PI 1.8378770664093453f

static constexpr unsigned INF_D2 = 62851u;   // > max real d2 (40^2 + 2*175^2 = 62850)

// ---------------------------------------------------------------- helpers
__device__ __forceinline__ void insert_key(unsigned (&t)[TOPK], unsigned key) {
    // t ascending; branch-free exact insert of key into 10 smallest.
#pragma unroll
    for (int i = TOPK - 1; i >= 1; --i) {
        unsigned hi = key > t[i - 1] ? key : t[i - 1];
        t[i] = hi < t[i] ? hi : t[i];
    }
    t[0] = key < t[0] ? key : t[0];
}

__device__ __forceinline__ void merge10(unsigned (&t)[TOPK], int lane,
                                        unsigned& mine, unsigned& first, unsigned& tenth) {
#pragma unroll
    for (int r = 0; r < TOPK; ++r) {
        unsigned v = t[0];
#pragma unroll
        for (int off = 32; off >= 1; off >>= 1) {
            unsigned o = __shfl_xor(v, off, 64);
            v = o < v ? o : v;
        }
        if (t[0] == v) {                       // unique keys -> exactly one popper
#pragma unroll
            for (int i = 0; i < TOPK - 1; ++i) t[i] = t[i + 1];
            t[TOPK - 1] = 0xFFFFFFFFu;
        }
        if (lane == r) mine = v;
        if (r == 0) first = v;
        if (r == TOPK - 1) tenth = v;
    }
}

__device__ __forceinline__ float waveReduceSum(float v) {
#pragma unroll
    for (int off = 32; off >= 1; off >>= 1) v += __shfl_down(v, off, 64);
    return v;
}

// scan candidates in [s,e) of a y-sorted batch partition (uint2, for rescans)
__device__ __forceinline__ void scan_range(unsigned (&t)[TOPK], const uint2* __restrict__ base,
                                           int s, int e, int rz, int ry, int rx, int lane) {
    for (int i = s + lane; i < e; i += 64) {
        uint2 c = base[i];
        int dz = (int)((c.x >> 16) & 63u)  - rz;
        int dy = (int)((c.x >> 8)  & 255u) - ry;
        int dx = (int)(c.x & 255u)         - rx;
        unsigned d2 = (unsigned)(__mul24(dz, dz) + __mul24(dy, dy) + __mul24(dx, dx));
        unsigned key = (d2 << 14) | c.y;
        if (key < t[TOPK - 1]) insert_key(t, key);
    }
}

// ---------------------------------------------------------------- prep
// 4 blocks x 1024 threads; block b owns batch b. Counting-sort the batch's
// lidar by y (176 bins) into compacted; LDS histogram + wave-parallel shfl
// prefix scan. Emits per-batch bin offsets so topk can scan a y-window.
__global__ __launch_bounds__(1024) void prep_kernel(
        const int* __restrict__ lidar_indices,
        unsigned* __restrict__ packed_full,
        uint2* __restrict__ compacted,
        int* __restrict__ binoff_g) {
    __shared__ int hist[NBIN];
    __shared__ int binoff_s[NBIN + 1];
    __shared__ int bcur[NBIN];
    int tid = threadIdx.x, myb = blockIdx.x;
    if (tid < NBIN) hist[tid] = 0;

    // stage ALL loads up-front (static indices -> registers, latencies overlap)
    int4 li[NLID / 1024];
#pragma unroll
    for (int it = 0; it < NLID / 1024; ++it)
        li[it] = ((const int4*)lidar_indices)[it * 1024 + tid];
    __syncthreads();

    // histogram over y (= column 2, li.z)
#pragma unroll
    for (int it = 0; it < NLID / 1024; ++it)
        if (li[it].x == myb) atomicAdd(&hist[li[it].z], 1);
    __syncthreads();

    // exclusive prefix: wave 0 only, shfl_up scan over 3 chunks of 64
    if (tid < 64) {
        int carry = 0;
#pragma unroll
        for (int c = 0; c < 3; ++c) {
            int idx = c * 64 + tid;
            int h = (idx < NBIN) ? hist[idx] : 0;
            int v = h;
#pragma unroll
            for (int off = 1; off < 64; off <<= 1) {
                int u = __shfl_up(v, off, 64);
                if (tid >= off) v += u;
            }
            if (idx < NBIN) binoff_s[idx] = carry + v - h;   // exclusive
            carry += __shfl(v, 63, 64);
        }
        if (tid == 0) binoff_s[NBIN] = carry;
    }
    __syncthreads();
    if (tid < NBIN) bcur[tid] = binoff_s[tid];
    __syncthreads();

    // scatter: y-sorted compacted + packed_full for the degenerate fallback
#pragma unroll
    for (int it = 0; it < NLID / 1024; ++it) {
        int i = it * 1024 + tid;
        unsigned pos = ((unsigned)li[it].y << 16) | ((unsigned)li[it].z << 8) | (unsigned)li[it].w;
        if (li[it].x == myb) {
            packed_full[i] = ((unsigned)li[it].x << 22) | pos;
            int dst = atomicAdd(&bcur[li[it].z], 1);
            compacted[myb * NLID + dst] = make_uint2(pos, (unsigned)i);
        }
    }

    __syncthreads();
    if (tid <= NBIN) binoff_g[myb * (NBIN + 1) + tid] = binoff_s[tid];
}

// ---------------------------------------------------------------- fused top-10 NN + MDN
// One wave per radar row (4 rows/block). y-window scan with exact accept test;
// rare reject rescans the remaining strips; <10-in-batch rows use the full
// packed scan. The block's 4 waves hand {row, matched, nn[10]} to LDS; wave 0
// alone computes the 40 MDN pairs (one per lane — same total work as a
// dedicated dispatch) and writes ONE plain float4 partial per block.
// NO atomics, NO threadfence in this kernel (r6 lesson: the per-block
// atomic+fence finalize protocol at 1024 blocks cost ~45 us serialized).
__global__ __launch_bounds__(256) void topk_mdn_kernel(
        const uint2* __restrict__ compacted,
        const unsigned* __restrict__ packed_full,
        const int* __restrict__ binoff_g,
        const int* __restrict__ radar_indices,
        const int* __restrict__ lidar_indices,
        const float* __restrict__ mu_off, const float* __restrict__ log_sig_off,
        const float* __restrict__ mu_int, const float* __restrict__ occ_logit,
        const float* __restrict__ mix_logit, const float* __restrict__ lidar_features,
        float4* __restrict__ partials) {      // [NRAD/4] per-block {lp,ip,oc,mc}
    int lane = threadIdx.x & 63;
    int wid  = threadIdx.x >> 6;
    int row  = blockIdx.x * 4 + wid;
    int4 ri = ((const int4*)radar_indices)[row];
    int rb = ri.x, rz = ri.y, ry = ri.z, rx = ri.w;
    const int* boff = binoff_g + rb * (NBIN + 1);

    int lo = ry - YWIN;      lo = lo < 0 ? 0 : lo;
    int hi = ry + YWIN + 1;  hi = hi > NBIN ? NBIN : hi;
    int s = boff[lo], e = boff[hi];

    unsigned t[TOPK];
#pragma unroll
    for (int i = 0; i < TOPK; ++i) t[i] = 0xFFFFFFFFu;

    const uint2* base = compacted + rb * NLID;
    int s0 = s & ~1;                                     // even -> 16B aligned
    const uint4* src4 = (const uint4*)(base + s0);
    int iters = (e - s0 + 127) >> 7;
    uint4 q = src4[lane];                                // stays in-partition
    for (int it = 0; it < iters; ++it) {
        uint4 qn = q;
        if (it + 1 < iters) qn = src4[(it + 1) * 64 + lane];   // prefetch next
        int p = s0 + (it * 64 + lane) * 2;
        {
            int dz = (int)((q.x >> 16) & 63u)  - rz;
            int dy = (int)((q.x >> 8)  & 255u) - ry;
            int dx = (int)(q.x & 255u)         - rx;
            unsigned d2 = (unsigned)(__mul24(dz, dz) + __mul24(dy, dy) + __mul24(dx, dx));
            unsigned key = (p >= s && p < e) ? ((d2 << 14) | q.y) : 0xFFFFFFFFu;
            if (key < t[TOPK - 1]) insert_key(t, key);
        }
        {
            int dz = (int)((q.z >> 16) & 63u)  - rz;
            int dy = (int)((q.z >> 8)  & 255u) - ry;
            int dx = (int)(q.z & 255u)         - rx;
            unsigned d2 = (unsigned)(__mul24(dz, dz) + __mul24(dy, dy) + __mul24(dx, dx));
            unsigned key = (p + 1 < e) ? ((d2 << 14) | q.w) : 0xFFFFFFFFu;
            if (key < t[TOPK - 1]) insert_key(t, key);
        }
        q = qn;
    }

    unsigned mine = 0xFFFFFFFFu, first = 0, tenth = 0;
    merge10(t, lane, mine, first, tenth);
    bool matched = true;

    // closest possible d2 outside the window (INF if window clipped that side)
    unsigned lim = 0xFFFFFFFFu;
    if (lo > 0)    { unsigned d = (unsigned)(ry - lo + 1); unsigned v = d * d; lim = v < lim ? v : lim; }
    if (hi < NBIN) { unsigned d = (unsigned)(hi - ry);     unsigned v = d * d; lim = v < lim ? v : lim; }

    if ((tenth >> 14) >= lim) {
        // expand to the full batch range, excluding already-scanned [s,e)
#pragma unroll
        for (int i = 0; i < TOPK; ++i) t[i] = 0xFFFFFFFFu;
        t[0] = mine;                                   // reseed (lanes>=10: FFFF no-op)
        scan_range(t, base, boff[0], s, rz, ry, rx, lane);
        scan_range(t, base, e, boff[NBIN], rz, ry, rx, lane);
        merge10(t, lane, mine, first, tenth);
    }

    if (tenth == 0xFFFFFFFFu) {
        // Degenerate row (<10 same-batch lidar): exact full scan w/ INF keys.
#pragma unroll
        for (int i = 0; i < TOPK; ++i) t[i] = 0xFFFFFFFFu;
        for (int it = 0; it < NLID / 256; ++it) {
            uint4 p4 = ((const uint4*)packed_full)[it * 64 + lane];
            unsigned bse = it * 256 + lane * 4;
            unsigned ps[4] = {p4.x, p4.y, p4.z, p4.w};
#pragma unroll
            for (int j = 0; j < 4; ++j) {
                unsigned p = ps[j];
                int b  = (int)(p >> 22);
                int dz = (int)((p >> 16) & 63u)  - rz;
                int dy = (int)((p >> 8)  & 255u) - ry;
                int dx = (int)(p & 255u)         - rx;
                unsigned d2 = (unsigned)(__mul24(dz, dz) + __mul24(dy, dy) + __mul24(dx, dx));
                unsigned hi2 = (b == rb) ? d2 : INF_D2;
                insert_key(t, (hi2 << 14) | (bse + j));
            }
        }
        merge10(t, lane, mine, first, tenth);
        matched = first < (INF_D2 << 14);
    }

    // ---------------- hand off to wave 0 via LDS (192 B) ------------------
    __shared__ int   s_nn[4][TOPK];
    __shared__ int   s_row[4];
    __shared__ float s_mf[4];
    if (lane < TOPK) s_nn[wid][lane] = (int)(mine & 0x3FFFu);
    if (lane == 0) { s_row[wid] = row; s_mf[wid] = matched ? 1.f : 0.f; }
    __syncthreads();
    if (wid != 0) return;                  // waves 1-3 done; wave 0 owns 40 pairs

    bool act = lane < 4 * TOPK;
    int w  = lane / TOPK;                  // 0..3 (garbage for inactive: masked)
    int tt = lane - w * TOPK;
    int n   = act ? s_row[w] : 0;
    float mf = act ? s_mf[w] : 0.f;
    int nni = act ? s_nn[w][tt] : 0;

    int4 rr = ((const int4*)radar_indices)[n];
    int4 li = ((const int4*)lidar_indices)[nni];
    float y0 = mf * (float)(li.w - rr.w);
    float y1 = mf * (float)(li.z - rr.z);
    float y2 = mf * (float)(li.y - rr.y);

    float mix[KMIX];
    float mmax = -1e30f;
#pragma unroll
    for (int k = 0; k < KMIX; ++k) {
        mix[k] = mix_logit[n * KMIX + k];
        mmax = fmaxf(mmax, mix[k]);
    }
    float msum = 0.f;
#pragma unroll
    for (int k = 0; k < KMIX; ++k) msum += expf(mix[k] - mmax);
    float logZ = mmax + logf(msum);

    float lpost[KMIX];
    float pmax = -1e30f;
#pragma unroll
    for (int k = 0; k < KMIX; ++k) {
        int bidx = (n * KMIX + k) * 3;
        float mu0 = mu_off[bidx + 0], mu1 = mu_off[bidx + 1], mu2 = mu_off[bidx + 2];
        float l0 = log_sig_off[bidx + 0], l1 = log_sig_off[bidx + 1], l2 = log_sig_off[bidx + 2];
        float s0 = expf(2.f * l0) + 1e-12f;
        float s1 = expf(2.f * l1) + 1e-12f;
        float s2 = expf(2.f * l2) + 1e-12f;
        float d0 = y0 - mu0, d1 = y1 - mu1, d2v = y2 - mu2;
        float qv = d0 * d0 / s0 + d1 * d1 / s1 + d2v * d2v / s2
                 + 2.f * (l0 + l1 + l2) + 3.f * LOG2PI;
        lpost[k] = -0.5f * qv + (mix[k] - logZ);
        pmax = fmaxf(pmax, lpost[k]);
    }
    float ex[KMIX];
    float se = 0.f;
#pragma unroll
    for (int k = 0; k < KMIX; ++k) { ex[k] = expf(lpost[k] - pmax); se += ex[k]; }
    float logp = pmax + logf(se);

    float gt = 0.f;
    if (act && mf != 0.f) {
        const float* lf = lidar_features + nni * CF;
        gt = 0.25f * (lf[3] + lf[7] + lf[11] + lf[15]);
    }
    float inv_se = 1.f / se;
    float isum = 0.f;
#pragma unroll
    for (int k = 0; k < KMIX; ++k)
        isum += ex[k] * inv_se * fabsf(mu_int[n * KMIX + k] - gt);

    float lp = act ? mf * logp : 0.f;
    float ip = act ? mf * isum : 0.f;
    float oc = 0.f, mc = 0.f;
    if (act && tt == 0) {
        float oa = -1e30f;
#pragma unroll
        for (int k = 0; k < KMIX; ++k) oa = fmaxf(oa, occ_logit[n * KMIX + k]);
        float soft_abs = log1pf(expf(-fabsf(oa)));
        oc = mf * (soft_abs + fmaxf(-oa, 0.f)) + (1.f - mf) * (soft_abs + fmaxf(oa, 0.f));
        mc = mf;
    }

    lp = waveReduceSum(lp); ip = waveReduceSum(ip);
    oc = waveReduceSum(oc); mc = waveReduceSum(mc);
    if (lane == 0) partials[blockIdx.x] = make_float4(lp, ip, oc, mc);
}

// ---------------------------------------------------------------- finalize
// 1 block, 256 threads: reduce 1024 float4 partials (16 KB) -> out[0].
// Visibility via stream ordering (separate dispatch) -> no fences needed.
__global__ __launch_bounds__(256) void finalize_kernel(
        const float4* __restrict__ partials,
        float* __restrict__ out) {
    int tid = threadIdx.x, lane = tid & 63, wid = tid >> 6;
    float a = 0.f, b = 0.f, c = 0.f, d = 0.f;
    for (int j = tid; j < NRAD / 4; j += 256) {
        float4 p = partials[j];
        a += p.x; b += p.y; c += p.z; d += p.w;
    }
    a = waveReduceSum(a); b = waveReduceSum(b);
    c = waveReduceSum(c); d = waveReduceSum(d);
    __shared__ float sA[4], sB[4], sC[4], sD[4];
    if (lane == 0) { sA[wid] = a; sB[wid] = b; sC[wid] = c; sD[wid] = d; }
    __syncthreads();
    if (tid == 0) {
        a = sA[0] + sA[1] + sA[2] + sA[3];
        b = sB[0] + sB[1] + sB[2] + sB[3];
        c = sC[0] + sC[1] + sC[2] + sC[3];
        d = sD[0] + sD[1] + sD[2] + sD[3];
        float occ_loss = c / (float)NRAD;
        float mdn_nll  = -a / (d * (float)TOPK);
        float int_loss = b / (d * (float)TOPK * (float)KMIX);
        out[0] = 0.2f * occ_loss + mdn_nll + 0.1f * int_loss;
    }
}

// ---------------------------------------------------------------- launch
extern "C" void kernel_launch(void* const* d_in, const int* in_sizes, int n_in,
                              void* d_out, int out_size, void* d_ws, size_t ws_size,
                              hipStream_t stream) {
    const float* mu_off         = (const float*)d_in[0];
    const float* log_sig_off    = (const float*)d_in[1];
    const float* mu_int         = (const float*)d_in[2];
    const float* occ_logit      = (const float*)d_in[3];
    const float* mix_logit      = (const float*)d_in[4];
    const float* lidar_features = (const float*)d_in[5];
    const int*   radar_indices  = (const int*)d_in[6];
    const int*   lidar_indices  = (const int*)d_in[7];
    float* out = (float*)d_out;

    char* ws = (char*)d_ws;
    unsigned* packed_full = (unsigned*)(ws + 0);         //  64 KB
    uint2*    compacted   = (uint2*)(ws + 65536);        //  512 KB (y-sorted per batch)
    int*      binoff_g    = (int*)(ws + 589824);         //  4*177*4 = 2832 B
    float4*   partials    = (float4*)(ws + 593920);      //  1024*16 = 16 KB

    hipLaunchKernelGGL(prep_kernel, dim3(4), dim3(1024), 0, stream,
                       lidar_indices, packed_full, compacted, binoff_g);
    hipLaunchKernelGGL(topk_mdn_kernel, dim3(NRAD / 4), dim3(256), 0, stream,
                       compacted, packed_full, binoff_g, radar_indices, lidar_indices,
                       mu_off, log_sig_off, mu_int, occ_logit, mix_logit,
                       lidar_features, partials);
    hipLaunchKernelGGL(finalize_kernel, dim3(1), dim3(256), 0, stream,
                       partials, out);
}

// Round 8
// 104.456 us; speedup vs baseline: 1.2439x; 1.0014x over previous
//
#include <hip/hip_runtime.h>
#include <cstdint>

#define NRAD 4096
#define NLID 16384
#define KMIX 8
#define TOPK 10
#define CF   16
#define NBIN 176
#define YWIN 13
#define LOG2PI 1.8378770664093453f

static constexpr unsigned INF_D2 = 62851u;   // > max real d2 (40^2 + 2*175^2 = 62850)

// ---------------------------------------------------------------- helpers
__device__ __forceinline__ void insert_key(unsigned (&t)[TOPK], unsigned key) {
    // t ascending; branch-free exact insert of key into 10 smallest.
#pragma unroll
    for (int i = TOPK - 1; i >= 1; --i) {
        unsigned hi = key > t[i - 1] ? key : t[i - 1];
        t[i] = hi < t[i] ? hi : t[i];
    }
    t[0] = key < t[0] ? key : t[0];
}

__device__ __forceinline__ void merge10(unsigned (&t)[TOPK], int lane,
                                        unsigned& mine, unsigned& first, unsigned& tenth) {
#pragma unroll
    for (int r = 0; r < TOPK; ++r) {
        unsigned v = t[0];
#pragma unroll
        for (int off = 32; off >= 1; off >>= 1) {
            unsigned o = __shfl_xor(v, off, 64);
            v = o < v ? o : v;
        }
        if (t[0] == v) {                       // unique keys -> exactly one popper
#pragma unroll
            for (int i = 0; i < TOPK - 1; ++i) t[i] = t[i + 1];
            t[TOPK - 1] = 0xFFFFFFFFu;
        }
        if (lane == r) mine = v;
        if (r == 0) first = v;
        if (r == TOPK - 1) tenth = v;
    }
}

__device__ __forceinline__ float waveReduceSum(float v) {
#pragma unroll
    for (int off = 32; off >= 1; off >>= 1) v += __shfl_down(v, off, 64);
    return v;
}

// scan candidates in [s,e) of a y-sorted batch partition (uint2, for rescans)
__device__ __forceinline__ void scan_range(unsigned (&t)[TOPK], const uint2* __restrict__ base,
                                           int s, int e, int rz, int ry, int rx, int lane) {
    for (int i = s + lane; i < e; i += 64) {
        uint2 c = base[i];
        int dz = (int)((c.x >> 16) & 63u)  - rz;
        int dy = (int)((c.x >> 8)  & 255u) - ry;
        int dx = (int)(c.x & 255u)         - rx;
        unsigned d2 = (unsigned)(__mul24(dz, dz) + __mul24(dy, dy) + __mul24(dx, dx));
        unsigned key = (d2 << 14) | c.y;
        if (key < t[TOPK - 1]) insert_key(t, key);
    }
}

// ---------------------------------------------------------------- prep
// 4 blocks x 1024 threads; block b owns batch b. Counting-sort the batch's
// lidar by y (176 bins) into compacted; LDS histogram + wave-parallel shfl
// prefix scan. packed_full is written branch-free/coalesced by EVERY block
// (identical values -> benign race) instead of predicated inside the scatter.
__global__ __launch_bounds__(1024) void prep_kernel(
        const int* __restrict__ lidar_indices,
        unsigned* __restrict__ packed_full,
        uint2* __restrict__ compacted,
        int* __restrict__ binoff_g) {
    __shared__ int hist[NBIN];
    __shared__ int binoff_s[NBIN + 1];
    __shared__ int bcur[NBIN];
    int tid = threadIdx.x, myb = blockIdx.x;
    if (tid < NBIN) hist[tid] = 0;

    // stage ALL loads up-front (static indices -> registers, latencies overlap)
    int4 li[NLID / 1024];
#pragma unroll
    for (int it = 0; it < NLID / 1024; ++it)
        li[it] = ((const int4*)lidar_indices)[it * 1024 + tid];

    // packed_full: branch-free coalesced stores (all blocks, identical data)
#pragma unroll
    for (int it = 0; it < NLID / 1024; ++it) {
        unsigned pos = ((unsigned)li[it].y << 16) | ((unsigned)li[it].z << 8) | (unsigned)li[it].w;
        packed_full[it * 1024 + tid] = ((unsigned)li[it].x << 22) | pos;
    }
    __syncthreads();

    // histogram over y (= column 2, li.z)
#pragma unroll
    for (int it = 0; it < NLID / 1024; ++it)
        if (li[it].x == myb) atomicAdd(&hist[li[it].z], 1);
    __syncthreads();

    // exclusive prefix: wave 0 only, shfl_up scan over 3 chunks of 64
    if (tid < 64) {
        int carry = 0;
#pragma unroll
        for (int c = 0; c < 3; ++c) {
            int idx = c * 64 + tid;
            int h = (idx < NBIN) ? hist[idx] : 0;
            int v = h;
#pragma unroll
            for (int off = 1; off < 64; off <<= 1) {
                int u = __shfl_up(v, off, 64);
                if (tid >= off) v += u;
            }
            if (idx < NBIN) binoff_s[idx] = carry + v - h;   // exclusive
            carry += __shfl(v, 63, 64);
        }
        if (tid == 0) binoff_s[NBIN] = carry;
    }
    __syncthreads();
    if (tid < NBIN) bcur[tid] = binoff_s[tid];
    __syncthreads();

    // scatter: y-sorted compacted (order within bin nondeterministic == fine,
    // keys carry the index tie-break)
#pragma unroll
    for (int it = 0; it < NLID / 1024; ++it) {
        int i = it * 1024 + tid;
        if (li[it].x == myb) {
            unsigned pos = ((unsigned)li[it].y << 16) | ((unsigned)li[it].z << 8) | (unsigned)li[it].w;
            int dst = atomicAdd(&bcur[li[it].z], 1);
            compacted[myb * NLID + dst] = make_uint2(pos, (unsigned)i);
        }
    }

    __syncthreads();
    if (tid <= NBIN) binoff_g[myb * (NBIN + 1) + tid] = binoff_s[tid];
}

// ---------------------------------------------------------------- fused top-10 NN + MDN
// One wave per radar row (4 rows/block). Wave 0's MDN row indices are known
// at kernel ENTRY (blockIdx*4+w), so all n-dependent MDN operands (64 floats
// per lane, 16 dwordx4 loads) are hoisted ABOVE the scan — their HBM/L2
// latency hides under the ~5 scan iterations. Only nni-dependent data
// (lidar_indices row, lidar_features) is loaded after the handoff.
// No atomics / no fences (r6 lesson); one plain float4 partial per block.
__global__ __launch_bounds__(256, 4) void topk_mdn_kernel(
        const uint2* __restrict__ compacted,
        const unsigned* __restrict__ packed_full,
        const int* __restrict__ binoff_g,
        const int* __restrict__ radar_indices,
        const int* __restrict__ lidar_indices,
        const float* __restrict__ mu_off, const float* __restrict__ log_sig_off,
        const float* __restrict__ mu_int, const float* __restrict__ occ_logit,
        const float* __restrict__ mix_logit, const float* __restrict__ lidar_features,
        float4* __restrict__ partials) {      // [NRAD/4] per-block {lp,ip,oc,mc}
    int lane = threadIdx.x & 63;
    int wid  = threadIdx.x >> 6;
    int row  = blockIdx.x * 4 + wid;

    // ---- wave-0 MDN operand prefetch (row-dependent, scan-independent) ----
    float mixv[KMIX], miv[KMIX], mu_[24], ls_[24];
    bool act = false; int w = 0, tt = 0, nmdn = 0;
    if (wid == 0) {
        act  = lane < 4 * TOPK;
        w    = act ? lane / TOPK : 0;          // clamp inactive lanes to a valid row
        tt   = act ? lane - w * TOPK : 0;
        nmdn = blockIdx.x * 4 + w;
        const float4* mxp = (const float4*)(mix_logit + nmdn * KMIX);
        const float4* mip = (const float4*)(mu_int   + nmdn * KMIX);
        float4 m0 = mxp[0], m1 = mxp[1], i0 = mip[0], i1 = mip[1];
        mixv[0]=m0.x; mixv[1]=m0.y; mixv[2]=m0.z; mixv[3]=m0.w;
        mixv[4]=m1.x; mixv[5]=m1.y; mixv[6]=m1.z; mixv[7]=m1.w;
        miv[0]=i0.x; miv[1]=i0.y; miv[2]=i0.z; miv[3]=i0.w;
        miv[4]=i1.x; miv[5]=i1.y; miv[6]=i1.z; miv[7]=i1.w;
        const float4* mop = (const float4*)(mu_off      + nmdn * 24);
        const float4* lsp = (const float4*)(log_sig_off + nmdn * 24);
#pragma unroll
        for (int j = 0; j < 6; ++j) {
            float4 a = mop[j], b = lsp[j];
            mu_[4*j]=a.x; mu_[4*j+1]=a.y; mu_[4*j+2]=a.z; mu_[4*j+3]=a.w;
            ls_[4*j]=b.x; ls_[4*j+1]=b.y; ls_[4*j+2]=b.z; ls_[4*j+3]=b.w;
        }
    }

    int4 ri = ((const int4*)radar_indices)[row];
    int rb = ri.x, rz = ri.y, ry = ri.z, rx = ri.w;
    const int* boff = binoff_g + rb * (NBIN + 1);

    int lo = ry - YWIN;      lo = lo < 0 ? 0 : lo;
    int hi = ry + YWIN + 1;  hi = hi > NBIN ? NBIN : hi;
    int s = boff[lo], e = boff[hi];

    unsigned t[TOPK];
#pragma unroll
    for (int i = 0; i < TOPK; ++i) t[i] = 0xFFFFFFFFu;

    const uint2* base = compacted + rb * NLID;
    int s0 = s & ~1;                                     // even -> 16B aligned
    const uint4* src4 = (const uint4*)(base + s0);
    int iters = (e - s0 + 127) >> 7;
    uint4 q = src4[lane];                                // stays in-partition
    for (int it = 0; it < iters; ++it) {
        uint4 qn = q;
        if (it + 1 < iters) qn = src4[(it + 1) * 64 + lane];   // prefetch next
        int p = s0 + (it * 64 + lane) * 2;
        {
            int dz = (int)((q.x >> 16) & 63u)  - rz;
            int dy = (int)((q.x >> 8)  & 255u) - ry;
            int dx = (int)(q.x & 255u)         - rx;
            unsigned d2 = (unsigned)(__mul24(dz, dz) + __mul24(dy, dy) + __mul24(dx, dx));
            unsigned key = (p >= s && p < e) ? ((d2 << 14) | q.y) : 0xFFFFFFFFu;
            if (key < t[TOPK - 1]) insert_key(t, key);
        }
        {
            int dz = (int)((q.z >> 16) & 63u)  - rz;
            int dy = (int)((q.z >> 8)  & 255u) - ry;
            int dx = (int)(q.z & 255u)         - rx;
            unsigned d2 = (unsigned)(__mul24(dz, dz) + __mul24(dy, dy) + __mul24(dx, dx));
            unsigned key = (p + 1 < e) ? ((d2 << 14) | q.w) : 0xFFFFFFFFu;
            if (key < t[TOPK - 1]) insert_key(t, key);
        }
        q = qn;
    }

    unsigned mine = 0xFFFFFFFFu, first = 0, tenth = 0;
    merge10(t, lane, mine, first, tenth);
    bool matched = true;

    // closest possible d2 outside the window (INF if window clipped that side)
    unsigned lim = 0xFFFFFFFFu;
    if (lo > 0)    { unsigned d = (unsigned)(ry - lo + 1); unsigned v = d * d; lim = v < lim ? v : lim; }
    if (hi < NBIN) { unsigned d = (unsigned)(hi - ry);     unsigned v = d * d; lim = v < lim ? v : lim; }

    if ((tenth >> 14) >= lim) {
        // expand to the full batch range, excluding already-scanned [s,e)
#pragma unroll
        for (int i = 0; i < TOPK; ++i) t[i] = 0xFFFFFFFFu;
        t[0] = mine;                                   // reseed (lanes>=10: FFFF no-op)
        scan_range(t, base, boff[0], s, rz, ry, rx, lane);
        scan_range(t, base, e, boff[NBIN], rz, ry, rx, lane);
        merge10(t, lane, mine, first, tenth);
    }

    if (tenth == 0xFFFFFFFFu) {
        // Degenerate row (<10 same-batch lidar): exact full scan w/ INF keys.
#pragma unroll
        for (int i = 0; i < TOPK; ++i) t[i] = 0xFFFFFFFFu;
        for (int it = 0; it < NLID / 256; ++it) {
            uint4 p4 = ((const uint4*)packed_full)[it * 64 + lane];
            unsigned bse = it * 256 + lane * 4;
            unsigned ps[4] = {p4.x, p4.y, p4.z, p4.w};
#pragma unroll
            for (int j = 0; j < 4; ++j) {
                unsigned p = ps[j];
                int b  = (int)(p >> 22);
                int dz = (int)((p >> 16) & 63u)  - rz;
                int dy = (int)((p >> 8)  & 255u) - ry;
                int dx = (int)(p & 255u)         - rx;
                unsigned d2 = (unsigned)(__mul24(dz, dz) + __mul24(dy, dy) + __mul24(dx, dx));
                unsigned hi2 = (b == rb) ? d2 : INF_D2;
                insert_key(t, (hi2 << 14) | (bse + j));
            }
        }
        merge10(t, lane, mine, first, tenth);
        matched = first < (INF_D2 << 14);
    }

    // ---------------- hand off to wave 0 via LDS (176 B) ------------------
    __shared__ int   s_nn[4][TOPK];
    __shared__ float s_mf[4];
    if (lane < TOPK) s_nn[wid][lane] = (int)(mine & 0x3FFFu);
    if (lane == 0)   s_mf[wid] = matched ? 1.f : 0.f;
    __syncthreads();
    if (wid != 0) return;                  // waves 1-3 done; wave 0 owns 40 pairs

    float mf = act ? s_mf[w] : 0.f;
    int  nni = act ? s_nn[w][tt] : 0;

    int4 rr = ((const int4*)radar_indices)[nmdn];
    int4 li = ((const int4*)lidar_indices)[nni];
    float y0 = mf * (float)(li.w - rr.w);
    float y1 = mf * (float)(li.z - rr.z);
    float y2 = mf * (float)(li.y - rr.y);

    float mmax = -1e30f;
#pragma unroll
    for (int k = 0; k < KMIX; ++k) mmax = fmaxf(mmax, mixv[k]);
    float msum = 0.f;
#pragma unroll
    for (int k = 0; k < KMIX; ++k) msum += expf(mixv[k] - mmax);
    float logZ = mmax + logf(msum);

    float lpost[KMIX];
    float pmax = -1e30f;
#pragma unroll
    for (int k = 0; k < KMIX; ++k) {
        float mu0 = mu_[3*k], mu1 = mu_[3*k+1], mu2 = mu_[3*k+2];
        float l0  = ls_[3*k], l1  = ls_[3*k+1], l2  = ls_[3*k+2];
        float sg0 = expf(2.f * l0) + 1e-12f;
        float sg1 = expf(2.f * l1) + 1e-12f;
        float sg2 = expf(2.f * l2) + 1e-12f;
        float d0 = y0 - mu0, d1 = y1 - mu1, d2v = y2 - mu2;
        float qv = d0 * d0 / sg0 + d1 * d1 / sg1 + d2v * d2v / sg2
                 + 2.f * (l0 + l1 + l2) + 3.f * LOG2PI;
        lpost[k] = -0.5f * qv + (mixv[k] - logZ);
        pmax = fmaxf(pmax, lpost[k]);
    }
    float ex[KMIX];
    float se = 0.f;
#pragma unroll
    for (int k = 0; k < KMIX; ++k) { ex[k] = expf(lpost[k] - pmax); se += ex[k]; }
    float logp = pmax + logf(se);

    float gt = 0.f;
    if (act && mf != 0.f) {
        const float* lf = lidar_features + nni * CF;
        gt = 0.25f * (lf[3] + lf[7] + lf[11] + lf[15]);
    }
    float inv_se = 1.f / se;
    float isum = 0.f;
#pragma unroll
    for (int k = 0; k < KMIX; ++k)
        isum += ex[k] * inv_se * fabsf(miv[k] - gt);

    float lp = act ? mf * logp : 0.f;
    float ip = act ? mf * isum : 0.f;
    float oc = 0.f, mc = 0.f;
    if (act && tt == 0) {
        float oa = -1e30f;
#pragma unroll
        for (int k = 0; k < KMIX; ++k) oa = fmaxf(oa, occ_logit[nmdn * KMIX + k]);
        float soft_abs = log1pf(expf(-fabsf(oa)));
        oc = mf * (soft_abs + fmaxf(-oa, 0.f)) + (1.f - mf) * (soft_abs + fmaxf(oa, 0.f));
        mc = mf;
    }

    lp = waveReduceSum(lp); ip = waveReduceSum(ip);
    oc = waveReduceSum(oc); mc = waveReduceSum(mc);
    if (lane == 0) partials[blockIdx.x] = make_float4(lp, ip, oc, mc);
}

// ---------------------------------------------------------------- finalize
// 1 block x 1024 threads: one float4 partial per thread -> out[0].
// Visibility via stream ordering (separate dispatch) -> no fences needed.
__global__ __launch_bounds__(1024) void finalize_kernel(
        const float4* __restrict__ partials,
        float* __restrict__ out) {
    int tid = threadIdx.x, lane = tid & 63, wid = tid >> 6;   // 16 waves
    float4 p = partials[tid];
    float a = p.x, b = p.y, c = p.z, d = p.w;
    a = waveReduceSum(a); b = waveReduceSum(b);
    c = waveReduceSum(c); d = waveReduceSum(d);
    __shared__ float sA[16], sB[16], sC[16], sD[16];
    if (lane == 0) { sA[wid] = a; sB[wid] = b; sC[wid] = c; sD[wid] = d; }
    __syncthreads();
    if (tid == 0) {
        a = 0.f; b = 0.f; c = 0.f; d = 0.f;
#pragma unroll
        for (int j = 0; j < 16; ++j) { a += sA[j]; b += sB[j]; c += sC[j]; d += sD[j]; }
        float occ_loss = c / (float)NRAD;
        float mdn_nll  = -a / (d * (float)TOPK);
        float int_loss = b / (d * (float)TOPK * (float)KMIX);
        out[0] = 0.2f * occ_loss + mdn_nll + 0.1f * int_loss;
    }
}

// ---------------------------------------------------------------- launch
extern "C" void kernel_launch(void* const* d_in, const int* in_sizes, int n_in,
                              void* d_out, int out_size, void* d_ws, size_t ws_size,
                              hipStream_t stream) {
    const float* mu_off         = (const float*)d_in[0];
    const float* log_sig_off    = (const float*)d_in[1];
    const float* mu_int         = (const float*)d_in[2];
    const float* occ_logit      = (const float*)d_in[3];
    const float* mix_logit      = (const float*)d_in[4];
    const float* lidar_features = (const float*)d_in[5];
    const int*   radar_indices  = (const int*)d_in[6];
    const int*   lidar_indices  = (const int*)d_in[7];
    float* out = (float*)d_out;

    char* ws = (char*)d_ws;
    unsigned* packed_full = (unsigned*)(ws + 0);         //  64 KB
    uint2*    compacted   = (uint2*)(ws + 65536);        //  512 KB (y-sorted per batch)
    int*      binoff_g    = (int*)(ws + 589824);         //  4*177*4 = 2832 B
    float4*   partials    = (float4*)(ws + 593920);      //  1024*16 = 16 KB

    hipLaunchKernelGGL(prep_kernel, dim3(4), dim3(1024), 0, stream,
                       lidar_indices, packed_full, compacted, binoff_g);
    hipLaunchKernelGGL(topk_mdn_kernel, dim3(NRAD / 4), dim3(256), 0, stream,
                       compacted, packed_full, binoff_g, radar_indices, lidar_indices,
                       mu_off, log_sig_off, mu_int, occ_logit, mix_logit,
                       lidar_features, partials);
    hipLaunchKernelGGL(finalize_kernel, dim3(1), dim3(1024), 0, stream,
                       partials, out);
}